// Round 1
// baseline (400.122 us; speedup 1.0000x reference)
//
#include <hip/hip_runtime.h>
#include <hip/hip_bf16.h>

#define BQ 16
#define KMAXX 4096
#define DD 512
#define AA 512
#define MTOT (BQ * KMAXX)  // 65536

typedef __bf16 bf16x8 __attribute__((ext_vector_type(8)));
typedef __bf16 bf16x4 __attribute__((ext_vector_type(4)));
typedef float f32x4 __attribute__((ext_vector_type(4)));

typedef __attribute__((address_space(1))) const void* as1_cvp;
typedef __attribute__((address_space(3))) void* as3_vp;

__device__ __forceinline__ void load_lds16(const void* g, void* l) {
  __builtin_amdgcn_global_load_lds((as1_cvp)g, (as3_vp)l, 16, 0, 0);
}

// ---------------- prep: v_w (weight-norm), q = query@wq^T + wk_b, Wb = bf16(wk_w) -------------
__global__ void prep_kernel(const float* __restrict__ query,
                            const float* __restrict__ wq_w,
                            const float* __restrict__ wk_b,
                            const float* __restrict__ v_v,
                            const float* __restrict__ v_g,
                            const float* __restrict__ wk_w,
                            float* __restrict__ q_buf,
                            float* __restrict__ vw_buf,
                            __bf16* __restrict__ Wb) {
  const int blk = blockIdx.x, t = threadIdx.x;
  if (blk == 0) {
    __shared__ float red[256];
    float v0 = v_v[t], v1 = v_v[t + 256];
    red[t] = v0 * v0 + v1 * v1;
    __syncthreads();
    for (int off = 128; off > 0; off >>= 1) {
      if (t < off) red[t] += red[t + off];
      __syncthreads();
    }
    const float scale = v_g[0] * rsqrtf(red[0]);
    vw_buf[t] = v_v[t] * scale;
    vw_buf[t + 256] = v_v[t + 256] * scale;
  } else if (blk <= 32) {
    const int idx = (blk - 1) * 256 + t;
    const int b = idx >> 9, a = idx & 511;
    const float4* qp = (const float4*)(query + (size_t)b * DD);
    const float4* wp = (const float4*)(wq_w + (size_t)a * DD);
    float s = 0.f;
#pragma unroll 4
    for (int j = 0; j < DD / 4; ++j) {
      float4 x = qp[j], w = wp[j];
      s += x.x * w.x + x.y * w.y + x.z * w.z + x.w * w.w;
    }
    q_buf[idx] = s + wk_b[a];
  } else {
    const float4* src = (const float4*)wk_w;
    bf16x4* dst = (bf16x4*)Wb;
    for (int i = (blk - 33) * 256 + t; i < (AA * DD / 4); i += 64 * 256) {
      float4 v = src[i];
      bf16x4 o;
      o[0] = (__bf16)v.x; o[1] = (__bf16)v.y; o[2] = (__bf16)v.z; o[3] = (__bf16)v.w;
      dst[i] = o;
    }
  }
}

// ---------------- fp32 -> bf16 bulk convert ----------------
__global__ void cvt_kernel(const float4* __restrict__ in, bf16x4* __restrict__ out, int n4) {
  const int stride = gridDim.x * blockDim.x;
  for (int i = blockIdx.x * blockDim.x + threadIdx.x; i < n4; i += stride) {
    float4 v = in[i];
    bf16x4 o;
    o[0] = (__bf16)v.x; o[1] = (__bf16)v.y; o[2] = (__bf16)v.z; o[3] = (__bf16)v.w;
    out[i] = o;
  }
}

// ---------------- fused GEMM + tanh + v_w dot: e[m] += sum_a tanh(X@W^T + q)[m,a]*vw[a] -------
// Tile 128x128, BK=32, 4 waves (each 64x64 as 4x4 MFMA 16x16x32 tiles).
// LDS tiles row-major [row][32] bf16, flat order == global_load_lds lane order.
template <bool CONV>
__global__ __launch_bounds__(256) void gemm_tanh_kernel(const void* __restrict__ Xv,
                                                        const __bf16* __restrict__ Wb,
                                                        const float* __restrict__ q_buf,
                                                        const float* __restrict__ vw_buf,
                                                        float* __restrict__ e_out) {
  __shared__ __align__(16) __bf16 sA[128 * 32];
  __shared__ __align__(16) __bf16 sB[128 * 32];
  const int t = threadIdx.x;
  const int m0 = blockIdx.x * 128;
  const int n0 = blockIdx.y * 128;
  const int wave = t >> 6;
  const int lane = t & 63;
  const int lrow = lane & 15;
  const int lquad = lane >> 4;
  const int wm = (wave & 1) * 64;
  const int wn = (wave >> 1) * 64;
  const int srow = t >> 2;         // staging row (0..63), +64 for i=1
  const int skk = (t & 3) * 8;     // staging k offset

  f32x4 acc[4][4] = {};

  const __bf16* Xb = (const __bf16*)Xv;
  const float* Xf = (const float*)Xv;

  for (int k0 = 0; k0 < DD; k0 += 32) {
    // stage B (bf16 weights) via LDS-DMA
#pragma unroll
    for (int i = 0; i < 2; ++i) {
      const __bf16* g = Wb + (size_t)(n0 + i * 64 + srow) * DD + k0 + skk;
      load_lds16((const void*)g, (void*)(sB + i * 2048 + (t & ~63) * 8));
    }
    if (!CONV) {
#pragma unroll
      for (int i = 0; i < 2; ++i) {
        const __bf16* g = Xb + (size_t)(m0 + i * 64 + srow) * DD + k0 + skk;
        load_lds16((const void*)g, (void*)(sA + i * 2048 + (t & ~63) * 8));
      }
    } else {
#pragma unroll
      for (int i = 0; i < 2; ++i) {
        const float* g = Xf + (size_t)(m0 + i * 64 + srow) * DD + k0 + skk;
        float4 v0 = *(const float4*)g;
        float4 v1 = *(const float4*)(g + 4);
        bf16x8 o;
        o[0] = (__bf16)v0.x; o[1] = (__bf16)v0.y; o[2] = (__bf16)v0.z; o[3] = (__bf16)v0.w;
        o[4] = (__bf16)v1.x; o[5] = (__bf16)v1.y; o[6] = (__bf16)v1.z; o[7] = (__bf16)v1.w;
        *(bf16x8*)(sA + i * 2048 + t * 8) = o;
      }
    }
    __syncthreads();
    bf16x8 aF[4], bF[4];
#pragma unroll
    for (int mt = 0; mt < 4; ++mt)
      aF[mt] = *(const bf16x8*)(sA + (wm + mt * 16 + lrow) * 32 + lquad * 8);
#pragma unroll
    for (int nt = 0; nt < 4; ++nt)
      bF[nt] = *(const bf16x8*)(sB + (wn + nt * 16 + lrow) * 32 + lquad * 8);
#pragma unroll
    for (int mt = 0; mt < 4; ++mt)
#pragma unroll
      for (int nt = 0; nt < 4; ++nt)
        acc[mt][nt] = __builtin_amdgcn_mfma_f32_16x16x32_bf16(aF[mt], bF[nt], acc[mt][nt], 0, 0, 0);
    __syncthreads();
  }

  // epilogue: e_partial[row] = sum_a tanh(acc + q[b,a]) * vw[a]; C/D layout: col=lane&15, row=quad*4+reg
  const int bidx = m0 >> 12;  // m0 / 4096
  const float* qrow = q_buf + (size_t)bidx * AA;
#pragma unroll
  for (int mt = 0; mt < 4; ++mt) {
#pragma unroll
    for (int reg = 0; reg < 4; ++reg) {
      const int row = wm + mt * 16 + lquad * 4 + reg;
      float s = 0.f;
#pragma unroll
      for (int nt = 0; nt < 4; ++nt) {
        const int a = n0 + wn + nt * 16 + lrow;
        s += tanhf(acc[mt][nt][reg] + qrow[a]) * vw_buf[a];
      }
      s += __shfl_xor(s, 1);
      s += __shfl_xor(s, 2);
      s += __shfl_xor(s, 4);
      s += __shfl_xor(s, 8);
      if (lrow == 0) atomicAdd(&e_out[m0 + row], s);
    }
  }
}

// ---------------- per-batch monotonic scan: aw_k = p_k * exp(1 + sum_{j<k} log(1-p_j)) -------
// e buffer (input) and aw (output) share storage: in-place per element.
__global__ void scan_kernel(const float* __restrict__ noise, const float* __restrict__ r,
                            float* __restrict__ e_aw) {
  const int b = blockIdx.x, t = threadIdx.x;
  const float r0 = r[0];
  const int base = b * KMAXX + t * 16;
  float p[16], pre[16];
  float run = 0.f;
#pragma unroll
  for (int j = 0; j < 16; ++j) {
    const int idx = base + j;
    const float x = e_aw[idx] + r0 + noise[idx];
    const float pj = 1.f / (1.f + expf(-x));
    p[j] = pj;
    pre[j] = run;
    run += logf(fmaxf(1.f - pj, 1e-10f));
  }
  __shared__ float tot[256];
  tot[t] = run;
  __syncthreads();
  for (int off = 1; off < 256; off <<= 1) {
    float y = 0.f;
    if (t >= off) y = tot[t - off];
    __syncthreads();
    tot[t] += y;
    __syncthreads();
  }
  const float excl = tot[t] - run;  // exclusive prefix of thread totals
#pragma unroll
  for (int j = 0; j < 16; ++j) {
    e_aw[base + j] = p[j] * expf(1.f + excl + pre[j]);
  }
}

// ---------------- cv[b,v] = sum_k aw[b,k] * value[b,k,v], with dead-chunk early-out ----------
__global__ void cv_kernel(const float* __restrict__ value, const float* __restrict__ aw,
                          float* __restrict__ cv_out) {
  const int kc = blockIdx.x, b = blockIdx.y, t = threadIdx.x;
  __shared__ float saw[256];
  __shared__ int active;
  if (t == 0) active = 0;
  __syncthreads();
  const float w = aw[b * KMAXX + kc * 256 + t];
  saw[t] = w;
  if (w > 1e-12f) active = 1;
  __syncthreads();
  if (!active) return;
  const float2* vp = (const float2*)(value + ((size_t)b * KMAXX + kc * 256) * DD);
  float ax = 0.f, ay = 0.f;
#pragma unroll 4
  for (int j = 0; j < 256; ++j) {
    const float2 v = vp[(size_t)j * 256 + t];
    const float wj = saw[j];
    ax += wj * v.x;
    ay += wj * v.y;
  }
  atomicAdd(&cv_out[b * DD + 2 * t], ax);
  atomicAdd(&cv_out[b * DD + 2 * t + 1], ay);
}

extern "C" void kernel_launch(void* const* d_in, const int* in_sizes, int n_in,
                              void* d_out, int out_size, void* d_ws, size_t ws_size,
                              hipStream_t stream) {
  const float* key_enc = (const float*)d_in[0];
  const float* value = (const float*)d_in[1];
  const float* query = (const float*)d_in[2];
  const float* noise = (const float*)d_in[3];
  const float* wk_w = (const float*)d_in[4];
  const float* wk_b = (const float*)d_in[5];
  const float* wq_w = (const float*)d_in[6];
  const float* v_v = (const float*)d_in[7];
  const float* v_g = (const float*)d_in[8];
  const float* r = (const float*)d_in[9];

  float* out = (float*)d_out;
  float* cv_out = out;                 // [16][512]
  float* aw_out = out + BQ * DD;       // [16][4096]; doubles as e-buffer before the scan

  char* ws = (char*)d_ws;
  float* q_buf = (float*)(ws);                    // 32 KB
  float* vw_buf = (float*)(ws + 32 * 1024);       // 2 KB
  __bf16* Wb = (__bf16*)(ws + 48 * 1024);         // 512 KB
  __bf16* Xb = (__bf16*)(ws + (1 << 20));         // 64 MB (fast path only)
  const bool fast = ws_size >= (size_t)(1 << 20) + (size_t)MTOT * DD * sizeof(__bf16);

  // zero cv region + e region (whole output buffer)
  hipMemsetAsync(d_out, 0, (size_t)out_size * sizeof(float), stream);

  prep_kernel<<<97, 256, 0, stream>>>(query, wq_w, wk_b, v_v, v_g, wk_w, q_buf, vw_buf, Wb);

  dim3 gg(MTOT / 128, AA / 128);
  if (fast) {
    cvt_kernel<<<4096, 256, 0, stream>>>((const float4*)key_enc, (bf16x4*)Xb, MTOT * DD / 4);
    gemm_tanh_kernel<false><<<gg, 256, 0, stream>>>((const void*)Xb, Wb, q_buf, vw_buf, aw_out);
  } else {
    gemm_tanh_kernel<true><<<gg, 256, 0, stream>>>((const void*)key_enc, Wb, q_buf, vw_buf, aw_out);
  }

  scan_kernel<<<BQ, 256, 0, stream>>>(noise, r, aw_out);
  cv_kernel<<<dim3(16, BQ), 256, 0, stream>>>(value, aw_out, cv_out);
}

// Round 2
// 373.421 us; speedup vs baseline: 1.0715x; 1.0715x over previous
//
#include <hip/hip_runtime.h>
#include <hip/hip_bf16.h>

#define BQ 16
#define KMAXX 4096
#define DD 512
#define AA 512
#define MTOT (BQ * KMAXX)  // 65536

typedef __bf16 bf16x8 __attribute__((ext_vector_type(8)));
typedef __bf16 bf16x4 __attribute__((ext_vector_type(4)));
typedef float f32x4 __attribute__((ext_vector_type(4)));

typedef __attribute__((address_space(1))) const void* as1_cvp;
typedef __attribute__((address_space(3))) void* as3_vp;

__device__ __forceinline__ void load_lds16(const void* g, void* l) {
  __builtin_amdgcn_global_load_lds((as1_cvp)g, (as3_vp)l, 16, 0, 0);
}

// fast tanh: 1 - 2/(e^{2x}+1); exact at +-inf via rcp(inf)=0
__device__ __forceinline__ float fast_tanh(float x) {
  float e = __expf(2.f * x);
  return 1.f - 2.f * __builtin_amdgcn_rcpf(e + 1.f);
}

// ---------------- prep: v_w (weight-norm), q = query@wq^T + wk_b, Wb = bf16(wk_w) -------------
__global__ void prep_kernel(const float* __restrict__ query,
                            const float* __restrict__ wq_w,
                            const float* __restrict__ wk_b,
                            const float* __restrict__ v_v,
                            const float* __restrict__ v_g,
                            const float* __restrict__ wk_w,
                            float* __restrict__ q_buf,
                            float* __restrict__ vw_buf,
                            __bf16* __restrict__ Wb) {
  const int blk = blockIdx.x, t = threadIdx.x;
  if (blk == 0) {
    __shared__ float red[256];
    float v0 = v_v[t], v1 = v_v[t + 256];
    red[t] = v0 * v0 + v1 * v1;
    __syncthreads();
    for (int off = 128; off > 0; off >>= 1) {
      if (t < off) red[t] += red[t + off];
      __syncthreads();
    }
    const float scale = v_g[0] * rsqrtf(red[0]);
    vw_buf[t] = v_v[t] * scale;
    vw_buf[t + 256] = v_v[t + 256] * scale;
  } else if (blk <= 32) {
    const int idx = (blk - 1) * 256 + t;
    const int b = idx >> 9, a = idx & 511;
    const float4* qp = (const float4*)(query + (size_t)b * DD);
    const float4* wp = (const float4*)(wq_w + (size_t)a * DD);
    float s = 0.f;
#pragma unroll 4
    for (int j = 0; j < DD / 4; ++j) {
      float4 x = qp[j], w = wp[j];
      s += x.x * w.x + x.y * w.y + x.z * w.z + x.w * w.w;
    }
    q_buf[idx] = s + wk_b[a];
  } else {
    const float4* src = (const float4*)wk_w;
    bf16x4* dst = (bf16x4*)Wb;
    for (int i = (blk - 33) * 256 + t; i < (AA * DD / 4); i += 64 * 256) {
      float4 v = src[i];
      bf16x4 o;
      o[0] = (__bf16)v.x; o[1] = (__bf16)v.y; o[2] = (__bf16)v.z; o[3] = (__bf16)v.w;
      dst[i] = o;
    }
  }
}

// ---------------- fused GEMM + tanh + v_w dot: e[m] += sum_a tanh(X@W^T + q)[m,a]*vw[a] -------
// Tile 128x128, BK=64, 4 waves (each 64x64 as 4x4 MFMA 16x16x32 tiles).
// LDS layout: row stride 128 B (64 bf16); 16-B chunk c' holds logical chunk c = c' ^ (row&7)
// (XOR swizzle on the GLOBAL source column, so global_load_lds's base+lane*16 order is kept).
// A is fp32 in global: converted to bf16 during staging (X read exactly once from HBM).
__global__ __launch_bounds__(256) void gemm_tanh_kernel(const float* __restrict__ X,
                                                        const __bf16* __restrict__ Wb,
                                                        const float* __restrict__ q_buf,
                                                        const float* __restrict__ vw_buf,
                                                        float* __restrict__ e_out) {
  __shared__ __align__(16) __bf16 sA[128 * 64];
  __shared__ __align__(16) __bf16 sB[128 * 64];
  const int t = threadIdx.x;
  const int n0 = blockIdx.x * 128;   // 4 n-chunks vary fastest -> A-tile L3 reuse
  const int m0 = blockIdx.y * 128;
  const int wave = t >> 6;
  const int lane = t & 63;
  const int lrow = lane & 15;
  const int lquad = lane >> 4;
  const int wm = (wave & 1) * 64;
  const int wn = (wave >> 1) * 64;
  // staging coords: flat 16-B slot (i*4096 + t*16) -> row = i*32 + (t>>3), c' = t&7
  const int srow = t >> 3;                    // 0..31
  const int sc = (t & 7) ^ ((t >> 3) & 7);    // swizzled source chunk (8 elems)
  const int wbase16 = (t & ~63) * 16;         // wave-uniform LDS byte base

  f32x4 acc[4][4] = {};

  for (int k0 = 0; k0 < DD; k0 += 64) {
    // B (bf16 weights) via LDS-DMA, swizzled source column
#pragma unroll
    for (int i = 0; i < 4; ++i) {
      const __bf16* g = Wb + (size_t)(n0 + i * 32 + srow) * DD + k0 + sc * 8;
      load_lds16((const void*)g, (void*)((char*)sB + i * 4096 + wbase16));
    }
    // A: fp32 -> bf16 convert during staging, same swizzled layout
#pragma unroll
    for (int i = 0; i < 4; ++i) {
      const float* g = X + (size_t)(m0 + i * 32 + srow) * DD + k0 + sc * 8;
      float4 v0 = ((const float4*)g)[0];
      float4 v1 = ((const float4*)g)[1];
      bf16x8 o;
      o[0] = (__bf16)v0.x; o[1] = (__bf16)v0.y; o[2] = (__bf16)v0.z; o[3] = (__bf16)v0.w;
      o[4] = (__bf16)v1.x; o[5] = (__bf16)v1.y; o[6] = (__bf16)v1.z; o[7] = (__bf16)v1.w;
      *(bf16x8*)((char*)sA + i * 4096 + t * 16) = o;
    }
    __syncthreads();
#pragma unroll
    for (int kk = 0; kk < 2; ++kk) {
      bf16x8 aF[4], bF[4];
#pragma unroll
      for (int mt = 0; mt < 4; ++mt) {
        const int row = wm + mt * 16 + lrow;
        const int cp = (kk * 4 + lquad) ^ (row & 7);
        aF[mt] = *(const bf16x8*)((char*)sA + row * 128 + cp * 16);
      }
#pragma unroll
      for (int nt = 0; nt < 4; ++nt) {
        const int row = wn + nt * 16 + lrow;
        const int cp = (kk * 4 + lquad) ^ (row & 7);
        bF[nt] = *(const bf16x8*)((char*)sB + row * 128 + cp * 16);
      }
#pragma unroll
      for (int mt = 0; mt < 4; ++mt)
#pragma unroll
        for (int nt = 0; nt < 4; ++nt)
          acc[mt][nt] = __builtin_amdgcn_mfma_f32_16x16x32_bf16(aF[mt], bF[nt], acc[mt][nt], 0, 0, 0);
    }
    __syncthreads();
  }

  // epilogue: e_partial[row] = sum_a tanh(acc + q[b,a]) * vw[a]
  // C/D layout: col = lane&15, row = lquad*4 + reg
  const int bidx = m0 >> 12;
  const float* qrow = q_buf + (size_t)bidx * AA;
  float qv[4], vwv[4];
#pragma unroll
  for (int nt = 0; nt < 4; ++nt) {
    const int a = n0 + wn + nt * 16 + lrow;
    qv[nt] = qrow[a];
    vwv[nt] = vw_buf[a];
  }
#pragma unroll
  for (int mt = 0; mt < 4; ++mt) {
#pragma unroll
    for (int reg = 0; reg < 4; ++reg) {
      const int row = wm + mt * 16 + lquad * 4 + reg;
      float s = 0.f;
#pragma unroll
      for (int nt = 0; nt < 4; ++nt)
        s += fast_tanh(acc[mt][nt][reg] + qv[nt]) * vwv[nt];
      s += __shfl_xor(s, 1);
      s += __shfl_xor(s, 2);
      s += __shfl_xor(s, 4);
      s += __shfl_xor(s, 8);
      if (lrow == 0) atomicAdd(&e_out[m0 + row], s);
    }
  }
}

// ---------------- per-batch monotonic scan: aw_k = p_k * exp(1 + sum_{j<k} log(1-p_j)) -------
__global__ void scan_kernel(const float* __restrict__ noise, const float* __restrict__ r,
                            float* __restrict__ e_aw) {
  const int b = blockIdx.x, t = threadIdx.x;
  const float r0 = r[0];
  const int base = b * KMAXX + t * 16;
  float p[16], pre[16];
  float run = 0.f;
#pragma unroll
  for (int j = 0; j < 16; ++j) {
    const int idx = base + j;
    const float x = e_aw[idx] + r0 + noise[idx];
    const float pj = 1.f / (1.f + expf(-x));
    p[j] = pj;
    pre[j] = run;
    run += logf(fmaxf(1.f - pj, 1e-10f));
  }
  __shared__ float tot[256];
  tot[t] = run;
  __syncthreads();
  for (int off = 1; off < 256; off <<= 1) {
    float y = 0.f;
    if (t >= off) y = tot[t - off];
    __syncthreads();
    tot[t] += y;
    __syncthreads();
  }
  const float excl = tot[t] - run;
#pragma unroll
  for (int j = 0; j < 16; ++j) {
    e_aw[base + j] = p[j] * expf(1.f + excl + pre[j]);
  }
}

// ---------------- cv[b,v] = sum_k aw[b,k]*value[b,k,v]; dead-chunk early-out, V split x4 -----
__global__ void cv_kernel(const float* __restrict__ value, const float* __restrict__ aw,
                          float* __restrict__ cv_out) {
  const int kc = blockIdx.x, b = blockIdx.y, vq = blockIdx.z;
  const int t = threadIdx.x;  // 64 threads (one wave)
  __shared__ float saw[256];
  float4 w4 = *(const float4*)(aw + b * KMAXX + kc * 256 + t * 4);
  *(float4*)(saw + t * 4) = w4;
  const float mx = fmaxf(fmaxf(w4.x, w4.y), fmaxf(w4.z, w4.w));
  if (!__any(mx > 1e-12f)) return;  // whole 256-chunk dead -> contribution < 1e-9
  const float2* vp = (const float2*)(value + ((size_t)(b * KMAXX + kc * 256)) * DD + vq * 128);
  float ax = 0.f, ay = 0.f;
#pragma unroll 4
  for (int j = 0; j < 256; ++j) {
    const float2 v = vp[(size_t)j * 256 + t];
    const float wj = saw[j];
    ax += wj * v.x;
    ay += wj * v.y;
  }
  atomicAdd(&cv_out[b * DD + vq * 128 + 2 * t], ax);
  atomicAdd(&cv_out[b * DD + vq * 128 + 2 * t + 1], ay);
}

extern "C" void kernel_launch(void* const* d_in, const int* in_sizes, int n_in,
                              void* d_out, int out_size, void* d_ws, size_t ws_size,
                              hipStream_t stream) {
  const float* key_enc = (const float*)d_in[0];
  const float* value = (const float*)d_in[1];
  const float* query = (const float*)d_in[2];
  const float* noise = (const float*)d_in[3];
  const float* wk_w = (const float*)d_in[4];
  const float* wk_b = (const float*)d_in[5];
  const float* wq_w = (const float*)d_in[6];
  const float* v_v = (const float*)d_in[7];
  const float* v_g = (const float*)d_in[8];
  const float* r = (const float*)d_in[9];

  float* out = (float*)d_out;
  float* cv_out = out;            // [16][512]
  float* aw_out = out + BQ * DD;  // [16][4096]; doubles as e-buffer before the scan

  char* ws = (char*)d_ws;
  float* q_buf = (float*)(ws);               // 32 KB
  float* vw_buf = (float*)(ws + 32 * 1024);  // 2 KB
  __bf16* Wb = (__bf16*)(ws + 48 * 1024);    // 512 KB

  hipMemsetAsync(d_out, 0, (size_t)out_size * sizeof(float), stream);

  prep_kernel<<<97, 256, 0, stream>>>(query, wq_w, wk_b, v_v, v_g, wk_w, q_buf, vw_buf, Wb);

  dim3 gg(AA / 128, MTOT / 128);  // n fastest-varying -> 4 blocks share each A-tile via L3
  gemm_tanh_kernel<<<gg, 256, 0, stream>>>(key_enc, Wb, q_buf, vw_buf, aw_out);

  scan_kernel<<<BQ, 256, 0, stream>>>(noise, r, aw_out);
  cv_kernel<<<dim3(16, BQ, 4), 64, 0, stream>>>(value, aw_out, cv_out);
}